// Round 5
// baseline (170.721 us; speedup 1.0000x reference)
//
#include <hip/hip_runtime.h>
#include <hip/hip_bf16.h>

#define BATCH 2048
#define NNODES 512
#define HID 64
#define LN_EPS 1e-5f
#define NEG_SLOPE 0.01f

#define NTHREADS 256          // 4 waves
#define SUBS 2                // 16-row MFMA tiles per wave
#define ROWS 128              // 4 waves * 2 subs * 16 rows

typedef __attribute__((ext_vector_type(8))) short bf16x8;
typedef __attribute__((ext_vector_type(4))) float f32x4;

__device__ __forceinline__ short f2bf(float f) {
    union { __hip_bfloat16 h; short s; } u;
    u.h = __float2bfloat16(f);   // canonical RNE (R3/R4-verified)
    return u.s;
}

// Block = 1 node x 128 batch rows, 256 threads, NO LDS.
// All x loads issued first (8 outstanding dwordx4/wave), W load+convert
// overlaps their latency. Swapped-operand MFMA (R4-verified): lane owns
// batch row b0+rl+l16, hidden cols c*16+lg*4+i. Register LN epilogue.
__global__ __launch_bounds__(NTHREADS, 4) void wv_mfma3_kernel(
    const float* __restrict__ x,      // [B, N, H]
    const float* __restrict__ dec,    // [3, 4]
    const float* __restrict__ rec,    // [3, 4]
    const float* __restrict__ W,      // [N, H, H]
    const float* __restrict__ bias,   // [N, H]
    const float* __restrict__ gamma,  // [N, H]
    const float* __restrict__ beta,   // [N, H]
    const int*   __restrict__ scales, // [N]
    float* __restrict__ out)          // [B, N, H]
{
    const int tid  = threadIdx.x;
    const int wave = tid >> 6;
    const int lane = tid & 63;
    const int l16  = lane & 15;
    const int lg   = lane >> 4;      // 0..3

    const int node  = blockIdx.x >> 4;   // 0..511
    const int chunk = blockIdx.x & 15;   // 0..15
    const int b0    = chunk * ROWS;

    // ---- issue ALL x loads first: 2 subs x 4 dwordx4 per lane
    f32x4 xr[SUBS][4];
    #pragma unroll
    for (int sub = 0; sub < SUBS; ++sub) {
        const int row = b0 + wave * (SUBS * 16) + sub * 16 + l16;
        const float* p = x + ((size_t)row * NNODES + node) * HID + lg * 8;
        xr[sub][0] = *reinterpret_cast<const f32x4*>(p);
        xr[sub][1] = *reinterpret_cast<const f32x4*>(p + 4);
        xr[sub][2] = *reinterpret_cast<const f32x4*>(p + 32);
        xr[sub][3] = *reinterpret_cast<const f32x4*>(p + 36);
    }

    const int   sc   = scales[node];
    const float sfac = dec[sc * 4 + 1] + rec[sc * 4 + 1];

    // ---- W fragments (first mfma operand), overlap x-load latency:
    //      lane holds W[node][c*16+l16][s*32 + lg*8 + j]
    bf16x8 wf[4][2];
    const float* Wn = W + (size_t)node * HID * HID;
    #pragma unroll
    for (int c = 0; c < 4; ++c) {
        #pragma unroll
        for (int s = 0; s < 2; ++s) {
            const float* p = Wn + (c * 16 + l16) * HID + s * 32 + lg * 8;
            f32x4 w0 = *reinterpret_cast<const f32x4*>(p);
            f32x4 w1 = *reinterpret_cast<const f32x4*>(p + 4);
            bf16x8 f;
            f[0] = f2bf(w0[0]); f[1] = f2bf(w0[1]); f[2] = f2bf(w0[2]); f[3] = f2bf(w0[3]);
            f[4] = f2bf(w1[0]); f[5] = f2bf(w1[1]); f[6] = f2bf(w1[2]); f[7] = f2bf(w1[3]);
            wf[c][s] = f;
        }
    }

    // ---- per-lane epilogue params for cols c*16 + lg*4 .. +3
    f32x4 bb[4], gg[4], be[4];
    #pragma unroll
    for (int c = 0; c < 4; ++c) {
        const int pbase = node * HID + c * 16 + lg * 4;
        bb[c] = *reinterpret_cast<const f32x4*>(bias  + pbase);
        gg[c] = *reinterpret_cast<const f32x4*>(gamma + pbase);
        be[c] = *reinterpret_cast<const f32x4*>(beta  + pbase);
    }

    #pragma unroll
    for (int sub = 0; sub < SUBS; ++sub) {
        const int row = b0 + wave * (SUBS * 16) + sub * 16 + l16;

        bf16x8 af[2];
        #pragma unroll
        for (int s = 0; s < 2; ++s) {
            const f32x4 x0 = xr[sub][s * 2 + 0];
            const f32x4 x1 = xr[sub][s * 2 + 1];
            bf16x8 f;
            f[0] = f2bf(x0[0] * sfac); f[1] = f2bf(x0[1] * sfac);
            f[2] = f2bf(x0[2] * sfac); f[3] = f2bf(x0[3] * sfac);
            f[4] = f2bf(x1[0] * sfac); f[5] = f2bf(x1[1] * sfac);
            f[6] = f2bf(x1[2] * sfac); f[7] = f2bf(x1[3] * sfac);
            af[s] = f;
        }

        f32x4 acc[4];
        #pragma unroll
        for (int c = 0; c < 4; ++c) {
            acc[c][0] = 0.f; acc[c][1] = 0.f; acc[c][2] = 0.f; acc[c][3] = 0.f;
            acc[c] = __builtin_amdgcn_mfma_f32_16x16x32_bf16(wf[c][0], af[0], acc[c], 0, 0, 0);
            acc[c] = __builtin_amdgcn_mfma_f32_16x16x32_bf16(wf[c][1], af[1], acc[c], 0, 0, 0);
        }

        // ---- register epilogue (R4-verified): +bias, two-pass LN, leaky
        float pS = 0.f;
        #pragma unroll
        for (int c = 0; c < 4; ++c) {
            #pragma unroll
            for (int i = 0; i < 4; ++i) {
                acc[c][i] += bb[c][i];
                pS += acc[c][i];
            }
        }
        pS += __shfl_xor(pS, 16, 64);
        pS += __shfl_xor(pS, 32, 64);
        const float mu = pS * (1.0f / 64.0f);

        float qS = 0.f;
        #pragma unroll
        for (int c = 0; c < 4; ++c) {
            #pragma unroll
            for (int i = 0; i < 4; ++i) {
                const float d = acc[c][i] - mu;
                qS += d * d;
            }
        }
        qS += __shfl_xor(qS, 16, 64);
        qS += __shfl_xor(qS, 32, 64);
        const float var  = qS * (1.0f / 64.0f);
        const float rstd = 1.0f / sqrtf(var + LN_EPS);

        float* op = out + ((size_t)row * NNODES + node) * HID;
        #pragma unroll
        for (int c = 0; c < 4; ++c) {
            f32x4 o;
            #pragma unroll
            for (int i = 0; i < 4; ++i) {
                float v = (acc[c][i] - mu) * rstd * gg[c][i] + be[c][i];
                o[i] = v >= 0.f ? v : v * NEG_SLOPE;
            }
            *reinterpret_cast<f32x4*>(op + c * 16 + lg * 4) = o;
        }
    }
}

extern "C" void kernel_launch(void* const* d_in, const int* in_sizes, int n_in,
                              void* d_out, int out_size, void* d_ws, size_t ws_size,
                              hipStream_t stream) {
    const float* x      = (const float*)d_in[0];
    const float* dec    = (const float*)d_in[1];
    const float* rec    = (const float*)d_in[2];
    const float* W      = (const float*)d_in[3];
    const float* bias   = (const float*)d_in[4];
    const float* gamma  = (const float*)d_in[5];
    const float* beta   = (const float*)d_in[6];
    const int*   scales = (const int*)d_in[7];
    float* out = (float*)d_out;

    const int blocks = NNODES * (BATCH / ROWS);  // 512 * 16 = 8192
    wv_mfma3_kernel<<<blocks, NTHREADS, 0, stream>>>(
        x, dec, rec, W, bias, gamma, beta, scales, out);
}

// Round 6
// 121.725 us; speedup vs baseline: 1.4025x; 1.4025x over previous
//
#include <hip/hip_runtime.h>
#include <hip/hip_bf16.h>

#define BATCH 2048
#define NNODES 512
#define HID 64
#define LN_EPS 1e-5f
#define NEG_SLOPE 0.01f

#define NPB 4        // nodes per block (one per wave)
#define RPB 32       // batch rows per block (2 sub-tiles of 16)
#define SUBS 2
#define TSTR 68      // LDS t-row stride in floats (68 ≡ 4 mod 32: balanced banks)

typedef __attribute__((ext_vector_type(8))) short bf16x8;
typedef __attribute__((ext_vector_type(4))) float f32x4;

__device__ __forceinline__ short f2bf(float f) {
    union { __hip_bfloat16 h; short s; } u;
    u.h = __float2bfloat16(f);   // canonical RNE (R3/R4-verified)
    return u.s;
}

// Block = 4 consecutive nodes x 32 rows; wave w owns node ng*4+w (waves fully
// independent -> NO __syncthreads). Per 16-row sub: swapped-operand MFMA
// (lane row = l16, cols = c*16+lg*4+i; R4-verified), register LN (2+2 shfls),
// wave-private LDS repack, then nontemporal full-line stores (4 rows x 256B
// contiguous per instruction; out is write-once so bypass L2/L3 keeps x hot).
__global__ __launch_bounds__(256, 4) void wv_mfma4_kernel(
    const float* __restrict__ x,      // [B, N, H]
    const float* __restrict__ dec,    // [3, 4]
    const float* __restrict__ rec,    // [3, 4]
    const float* __restrict__ W,      // [N, H, H]
    const float* __restrict__ bias,   // [N, H]
    const float* __restrict__ gamma,  // [N, H]
    const float* __restrict__ beta,   // [N, H]
    const int*   __restrict__ scales, // [N]
    float* __restrict__ out)          // [B, N, H]
{
    __shared__ float tLds [NPB][16][TSTR];   // per-wave t tile (one sub)
    __shared__ float muLds[NPB][16];
    __shared__ float rsLds[NPB][16];

    const int tid  = threadIdx.x;
    const int wave = tid >> 6;
    const int lane = tid & 63;
    const int l16  = lane & 15;
    const int lg   = lane >> 4;      // 0..3

    const int ng   = blockIdx.x & 127;   // node group (minor: adjacent blocks = adjacent nodes)
    const int rc   = blockIdx.x >> 7;    // 0..63 row chunk
    const int node = ng * NPB + wave;
    const int b0   = rc * RPB;

    const int   sc   = scales[node];
    const float sfac = dec[sc * 4 + 1] + rec[sc * 4 + 1];

    // ---- W fragments (first mfma operand; R4-verified layout):
    //      lane holds W[node][c*16+l16][s*32 + lg*8 + j]
    bf16x8 wf[4][2];
    const float* Wn = W + (size_t)node * HID * HID;
    #pragma unroll
    for (int c = 0; c < 4; ++c) {
        #pragma unroll
        for (int s = 0; s < 2; ++s) {
            const float* p = Wn + (c * 16 + l16) * HID + s * 32 + lg * 8;
            f32x4 w0 = *reinterpret_cast<const f32x4*>(p);
            f32x4 w1 = *reinterpret_cast<const f32x4*>(p + 4);
            bf16x8 f;
            f[0] = f2bf(w0[0]); f[1] = f2bf(w0[1]); f[2] = f2bf(w0[2]); f[3] = f2bf(w0[3]);
            f[4] = f2bf(w1[0]); f[5] = f2bf(w1[1]); f[6] = f2bf(w1[2]); f[7] = f2bf(w1[3]);
            wf[c][s] = f;
        }
    }

    // ---- bias for MFMA-layout cols c*16 + lg*4 .. +3
    f32x4 bb[4];
    #pragma unroll
    for (int c = 0; c < 4; ++c)
        bb[c] = *reinterpret_cast<const f32x4*>(bias + node * HID + c * 16 + lg * 4);

    // ---- gamma/beta for epilogue-layout cols l16*4 .. +3
    const f32x4 gg = *reinterpret_cast<const f32x4*>(gamma + node * HID + l16 * 4);
    const f32x4 be = *reinterpret_cast<const f32x4*>(beta  + node * HID + l16 * 4);

    #pragma unroll
    for (int sub = 0; sub < SUBS; ++sub) {
        const int rowb = b0 + sub * 16;
        const int row  = rowb + l16;     // this lane's batch row in MFMA phase

        // ---- x fragments: 32B contiguous per lane per s-half
        const float* p = x + ((size_t)row * NNODES + node) * HID + lg * 8;
        f32x4 x0 = *reinterpret_cast<const f32x4*>(p);
        f32x4 x1 = *reinterpret_cast<const f32x4*>(p + 4);
        f32x4 x2 = *reinterpret_cast<const f32x4*>(p + 32);
        f32x4 x3 = *reinterpret_cast<const f32x4*>(p + 36);

        bf16x8 af0, af1;
        af0[0] = f2bf(x0[0] * sfac); af0[1] = f2bf(x0[1] * sfac);
        af0[2] = f2bf(x0[2] * sfac); af0[3] = f2bf(x0[3] * sfac);
        af0[4] = f2bf(x1[0] * sfac); af0[5] = f2bf(x1[1] * sfac);
        af0[6] = f2bf(x1[2] * sfac); af0[7] = f2bf(x1[3] * sfac);
        af1[0] = f2bf(x2[0] * sfac); af1[1] = f2bf(x2[1] * sfac);
        af1[2] = f2bf(x2[2] * sfac); af1[3] = f2bf(x2[3] * sfac);
        af1[4] = f2bf(x3[0] * sfac); af1[5] = f2bf(x3[1] * sfac);
        af1[6] = f2bf(x3[2] * sfac); af1[7] = f2bf(x3[3] * sfac);

        f32x4 acc[4];
        #pragma unroll
        for (int c = 0; c < 4; ++c) {
            acc[c][0] = 0.f; acc[c][1] = 0.f; acc[c][2] = 0.f; acc[c][3] = 0.f;
            acc[c] = __builtin_amdgcn_mfma_f32_16x16x32_bf16(wf[c][0], af0, acc[c], 0, 0, 0);
            acc[c] = __builtin_amdgcn_mfma_f32_16x16x32_bf16(wf[c][1], af1, acc[c], 0, 0, 0);
        }

        // ---- +bias and two-pass LN stats in registers (R4-verified)
        float pS = 0.f;
        #pragma unroll
        for (int c = 0; c < 4; ++c) {
            #pragma unroll
            for (int i = 0; i < 4; ++i) {
                acc[c][i] += bb[c][i];
                pS += acc[c][i];
            }
        }
        pS += __shfl_xor(pS, 16, 64);
        pS += __shfl_xor(pS, 32, 64);
        const float mu = pS * (1.0f / 64.0f);

        float qS = 0.f;
        #pragma unroll
        for (int c = 0; c < 4; ++c) {
            #pragma unroll
            for (int i = 0; i < 4; ++i) {
                const float d = acc[c][i] - mu;
                qS += d * d;
            }
        }
        qS += __shfl_xor(qS, 16, 64);
        qS += __shfl_xor(qS, 32, 64);
        const float rstd = 1.0f / sqrtf(qS * (1.0f / 64.0f) + LN_EPS);

        // ---- repack t through wave-private LDS (no cross-wave -> no barrier)
        #pragma unroll
        for (int c = 0; c < 4; ++c)
            *reinterpret_cast<f32x4*>(&tLds[wave][l16][c * 16 + lg * 4]) = acc[c];
        if (lg == 0) { muLds[wave][l16] = mu; rsLds[wave][l16] = rstd; }

        // ---- epilogue: lane (l16,lg) -> row k*4+lg, cols l16*4..+3
        #pragma unroll
        for (int k = 0; k < 4; ++k) {
            const int rl = k * 4 + lg;
            f32x4 tv = *reinterpret_cast<const f32x4*>(&tLds[wave][rl][l16 * 4]);
            const float m  = muLds[wave][rl];
            const float rs = rsLds[wave][rl];
            f32x4 o;
            #pragma unroll
            for (int i = 0; i < 4; ++i) {
                float v = (tv[i] - m) * rs * gg[i] + be[i];
                o[i] = v >= 0.f ? v : v * NEG_SLOPE;
            }
            __builtin_nontemporal_store(
                o, reinterpret_cast<f32x4*>(
                       out + ((size_t)(rowb + rl) * NNODES + node) * HID + l16 * 4));
        }
    }
}

extern "C" void kernel_launch(void* const* d_in, const int* in_sizes, int n_in,
                              void* d_out, int out_size, void* d_ws, size_t ws_size,
                              hipStream_t stream) {
    const float* x      = (const float*)d_in[0];
    const float* dec    = (const float*)d_in[1];
    const float* rec    = (const float*)d_in[2];
    const float* W      = (const float*)d_in[3];
    const float* bias   = (const float*)d_in[4];
    const float* gamma  = (const float*)d_in[5];
    const float* beta   = (const float*)d_in[6];
    const int*   scales = (const int*)d_in[7];
    float* out = (float*)d_out;

    const int blocks = (NNODES / NPB) * (BATCH / RPB);  // 128 * 64 = 8192
    wv_mfma4_kernel<<<blocks, 256, 0, stream>>>(
        x, dec, rec, W, bias, gamma, beta, scales, out);
}